// Round 7
// baseline (244.550 us; speedup 1.0000x reference)
//
#include <hip/hip_runtime.h>

// PrunedMultiHeadAttention: B=16,N=1024,C=768,H=9,HD=64
// All f16 operand matrices live in global memory XOR-chunk-swizzled:
//   within each aligned group of 8 16B-chunks (64 elems = one BK tile),
//   logical chunk c of row r is stored at position (c & ~7) | ((c ^ r) & 7).
// This makes global_load_lds (lane-linear DMA into unpadded stride-64/128 LDS)
// conflict-free on the MFMA b128 fragment reads (group = (4ks+hi)^(lo&7)).

typedef _Float16 f16x8 __attribute__((ext_vector_type(8)));
typedef _Float16 f16x4 __attribute__((ext_vector_type(4)));
typedef __fp16   h16x2 __attribute__((ext_vector_type(2)));  // cvt_pkrtz result type
typedef float    f32x4 __attribute__((ext_vector_type(4)));

#define MFMA16(a, b, c) __builtin_amdgcn_mfma_f32_16x16x32_f16(a, b, c, 0, 0, 0)

// async global->LDS DMA, 16B/lane; LDS dest = wave-uniform base + lane*16
__device__ __forceinline__ void gld16(const _Float16* g, _Float16* l) {
  __builtin_amdgcn_global_load_lds((const __attribute__((address_space(1))) void*)g,
                                   (__attribute__((address_space(3))) void*)l, 16, 0, 0);
}

// ---------------------------------------------------------------- convert + swizzle
// fp32 row-major [rows_src x (cpr*8)] -> fp16 swizzled [rows_dst x (cpr*8)], zero-pad rows >= rows_src
__global__ __launch_bounds__(256) void cvt_swz(const float* __restrict__ src,
                                               _Float16* __restrict__ dst,
                                               int rows_src, int cpr, int total) {
  const int g = blockIdx.x * 256 + threadIdx.x;
  if (g >= total) return;
  const int row = g / cpr;
  const int c = g - row * cpr;
  const int L = cpr * 8;
  const int pos = (c & ~7) | ((c ^ row) & 7);
  union { f16x8 v; h16x2 h[4]; } u;
  if (row < rows_src) {
    const float4 a = *(const float4*)(src + row * L + c * 8);
    const float4 b = *(const float4*)(src + row * L + c * 8 + 4);
    u.h[0] = __builtin_amdgcn_cvt_pkrtz(a.x, a.y);
    u.h[1] = __builtin_amdgcn_cvt_pkrtz(a.z, a.w);
    u.h[2] = __builtin_amdgcn_cvt_pkrtz(b.x, b.y);
    u.h[3] = __builtin_amdgcn_cvt_pkrtz(b.z, b.w);
  } else {
    u.v = (f16x8){};
  }
  *(f16x8*)(dst + row * L + pos * 8) = u.v;
}

// ---------------------------------------------------------------- GEMM1: qkv = x @ W^T + b
// A: x16 swz [16384,768], Bw: w1 swz padded [1792,768] (rows >=1728 zero)
// Q -> [B,H,N,64] plain; K -> [B,H,N,64] swizzled; V -> [B,H,64,N] transposed+swizzled
// 1-D grid 1792 = 8 XCD x 16 m-tiles x 14 n-tiles, n-inner: each 196KB A-panel
// stays L2-hot for 14 consecutive same-XCD blocks; full B (2.65MB) L2-resident/XCD.
__global__ __launch_bounds__(256, 4) void gemm1_qkv(const _Float16* __restrict__ A,
                                                    const _Float16* __restrict__ Bw,
                                                    const float* __restrict__ bias,
                                                    _Float16* __restrict__ Qo,
                                                    _Float16* __restrict__ Ko,
                                                    _Float16* __restrict__ Vt) {
  __shared__ __align__(16) _Float16 As[128 * 64];
  __shared__ __align__(16) _Float16 Bs[128 * 64];
  const int tid = threadIdx.x;
  const int wave = tid >> 6, lane = tid & 63;
  const int lo = lane & 15, hi = lane >> 4;
  const int wm = (wave >> 1) * 64, wn = (wave & 1) * 64;
  const int g = blockIdx.x;
  const int xcd = g & 7, i = g >> 3;            // i in [0,224)
  const int mt = i / 14, ntl = i - mt * 14;     // 16 m-tiles/XCD, 14 n-tiles
  const int m0 = (xcd * 16 + mt) * 128, n0 = ntl * 128;
  f32x4 acc[4][4] = {};
  for (int k0 = 0; k0 < 768; k0 += 64) {
    __syncthreads();
    #pragma unroll
    for (int j = 0; j < 4; ++j) {
      const int seg = wave * 4 + j;
      const int gr = seg * 8 + (lane >> 3), gc = (lane & 7) << 3;
      gld16(A + (m0 + gr) * 768 + k0 + gc, As + seg * 512);
      gld16(Bw + (n0 + gr) * 768 + k0 + gc, Bs + seg * 512);
    }
    __syncthreads();
    #pragma unroll
    for (int ks = 0; ks < 2; ++ks) {
      f16x8 af[4], bf[4];
      const int p = ((ks * 4 + hi) ^ (lo & 7)) << 3;
      #pragma unroll
      for (int t = 0; t < 4; ++t) {
        af[t] = *(const f16x8*)(As + (wm + t * 16 + lo) * 64 + p);
        bf[t] = *(const f16x8*)(Bs + (wn + t * 16 + lo) * 64 + p);
      }
      #pragma unroll
      for (int mt2 = 0; mt2 < 4; ++mt2)
        #pragma unroll
        for (int nt = 0; nt < 4; ++nt)
          acc[mt2][nt] = MFMA16(af[mt2], bf[nt], acc[mt2][nt]);
    }
  }
  // epilogue: C/D layout col=lane&15 (n), row=(lane>>4)*4+i (m)
  const int b = m0 >> 10;
  const int nrbase = (m0 & 1023) + wm;
  #pragma unroll
  for (int nt = 0; nt < 4; ++nt) {
    const int n = n0 + wn + nt * 16 + lo;
    if (n < 1728) {   // wave-uniform: 16-wide n-group never crosses a 576 boundary
      const float bv = bias[n];
      const int t3 = n / 576;
      const int rem = n - t3 * 576;
      const int hh = rem >> 6, d = rem & 63;
      const int bh16 = (b * 9 + hh) << 16;
      if (t3 == 2) {
        // V transposed + swizzled: element (d, t): chunk c=t>>3, pos=(c&~7)|((c^d)&7)
        _Float16* dv = Vt + bh16 + d * 1024;
        #pragma unroll
        for (int mt2 = 0; mt2 < 4; ++mt2) {
          const int nr = nrbase + mt2 * 16 + hi * 4;
          const int c = nr >> 3;
          const int pos = (c & ~7) | ((c ^ d) & 7);
          union { f16x4 v; h16x2 h[2]; } u;
          u.h[0] = __builtin_amdgcn_cvt_pkrtz(acc[mt2][nt][0] + bv, acc[mt2][nt][1] + bv);
          u.h[1] = __builtin_amdgcn_cvt_pkrtz(acc[mt2][nt][2] + bv, acc[mt2][nt][3] + bv);
          *(f16x4*)(dv + pos * 8 + (nr & 7)) = u.v;
        }
      } else if (t3 == 1) {
        // K swizzled: element (t, d) at t*64 + ((d>>3 ^ (t&7))<<3) + (d&7)
        _Float16* dk = Ko + bh16;
        const int ch = d >> 3, dl = d & 7;
        #pragma unroll
        for (int mt2 = 0; mt2 < 4; ++mt2) {
          const int nr = nrbase + mt2 * 16 + hi * 4;
          #pragma unroll
          for (int i2 = 0; i2 < 4; ++i2) {
            const int t = nr + i2;
            dk[t * 64 + ((ch ^ (t & 7)) << 3) + dl] = (_Float16)(acc[mt2][nt][i2] + bv);
          }
        }
      } else {
        _Float16* dq = Qo + bh16 + d;   // Q plain row-major
        #pragma unroll
        for (int mt2 = 0; mt2 < 4; ++mt2) {
          const int nr = nrbase + mt2 * 16 + hi * 4;
          #pragma unroll
          for (int i2 = 0; i2 < 4; ++i2)
            dq[(nr + i2) * 64] = (_Float16)(acc[mt2][nt][i2] + bv);
        }
      }
    }
  }
}

// ---------------------------------------------------------------- flash attention (pipelined, 8 waves)
// S^T = K·Q^T, O^T = V^T·P^T.  128 q rows/block (8 waves x 16 q), K-tile 64,
// K AND V double-buffered (round-5 proven cover), counted vmcnt(2) waits:
// each wave issues 1 K + 1 V gld16 per step; the wait drains ops issued one
// full tile earlier, so prefetch latency hides under a whole tile's compute.
// 8 waves share each K/V tile -> per-wave DMA and HBM fetch HALVED vs the
// 4-wave/64q version; grid halves to 1152.
// LDS: Ks[2][64x64] 16KB + Vts[2][64x64] 16KB + Ps[8][16x64] 16KB = 48KB
//   -> 3 blocks/CU x 8 waves = 24 resident waves/CU (vs 16 at round-5 cap 4;
//   round 6 showed an exact 160KB fit does NOT schedule, so 48x3=144KB keeps
//   slack). Ps is wave-private.
// Q consumed directly from global; T13 defer-max; no setprio (lockstep barriers).
__global__ __launch_bounds__(512, 6) void attn_fused(const _Float16* __restrict__ Qg,
                                                     const _Float16* __restrict__ Kg,
                                                     const _Float16* __restrict__ Vtg,
                                                     _Float16* __restrict__ Og) {
  __shared__ __align__(16) _Float16 Ks[2][64 * 64];
  __shared__ __align__(16) _Float16 Vts[2][64 * 64];
  __shared__ __align__(16) _Float16 Ps[8][16 * 64];
  const int tid = threadIdx.x;
  const int wave = tid >> 6, lane = tid & 63;
  const int lo = lane & 15, hi = lane >> 4;
  // XCD-major block mapping: bid%8 = XCD, 18 heads x 8 q-blocks(128 rows) per XCD
  const int bid = blockIdx.x;
  const int xcd = bid & 7, idx = bid >> 3;      // idx 0..143
  const int bh = xcd * 18 + (idx >> 3);         // 0..143
  const int q0 = (idx & 7) << 7;                // 0,128,...,896
  const _Float16* Qp  = Qg + (bh << 16);
  const _Float16* Kp  = Kg + (bh << 16);
  const _Float16* Vtp = Vtg + (bh << 16);

  // issue DMA for K/V tile starting at t0 into buffer nb (2 gld16/wave, 16/block)
  auto issue = [&](int t0, int nb) {
    const int seg = wave;                       // 8 segs of 8 rows each
    gld16(Kp + (t0 + seg * 8 + (lane >> 3)) * 64 + ((lane & 7) << 3), &Ks[nb][seg * 512]);
    gld16(Vtp + (seg * 8 + (lane >> 3)) * 1024 + t0 + ((lane & 7) << 3), &Vts[nb][seg * 512]);
  };

  issue(0, 0);   // prologue: tile 0 in flight

  // Q fragment straight from global: lane needs Q[q0+wave*16+lo][ (ks*4+hi)*8 .. +7 ]
  f16x8 qf[2];
  const _Float16* qrow = Qp + (q0 + wave * 16 + lo) * 64;
  qf[0] = *(const f16x8*)(qrow + hi * 8);
  qf[1] = *(const f16x8*)(qrow + (4 + hi) * 8);

  float m_run = -1e30f, l_run = 0.f;
  f32x4 accO[4] = {};
  const float cs = 0.125f * 1.44269504f;  // HD^-0.5 * log2(e)
  _Float16* Pw = Ps[wave];                // wave-private 16q x 64t, xor-swizzled

  auto compute = [&](int cb) {
    const _Float16* Kc = Ks[cb];
    const _Float16* Vc = Vts[cb];
    // S^T: C layout col=lo=q, row=hi*4+i (+16*tt) = t
    f32x4 sacc[4] = {};
    #pragma unroll
    for (int tt = 0; tt < 4; ++tt)
      #pragma unroll
      for (int ks = 0; ks < 2; ++ks) {
        const f16x8 kf = *(const f16x8*)(Kc + (tt * 16 + lo) * 64 + (((ks * 4 + hi) ^ (lo & 7)) << 3));
        sacc[tt] = MFMA16(kf, qf[ks], sacc[tt]);
      }
    float rmax = -1e30f;
    #pragma unroll
    for (int tt = 0; tt < 4; ++tt)
      rmax = fmaxf(rmax, fmaxf(fmaxf(sacc[tt][0], sacc[tt][1]), fmaxf(sacc[tt][2], sacc[tt][3])));
    rmax = fmaxf(rmax, __shfl_xor(rmax, 16, 64));
    rmax = fmaxf(rmax, __shfl_xor(rmax, 32, 64));
    // T13 defer-max: if no row's max grew by >8 (wave-uniform check), keep m_run;
    // P is then bounded by 2^8 (fine in f16) and the alpha-rescale is skipped.
    const float rs = rmax * cs;
    const bool nsk = !__all(rs <= m_run + 8.f);
    const float mnew = nsk ? fmaxf(m_run, rs) : m_run;
    const float alpha = nsk ? __builtin_amdgcn_exp2f(m_run - mnew) : 1.f;
    float rsum = 0.f;
    #pragma unroll
    for (int tt = 0; tt < 4; ++tt) {
      const float p0 = __builtin_amdgcn_exp2f(fmaf(sacc[tt][0], cs, -mnew));
      const float p1 = __builtin_amdgcn_exp2f(fmaf(sacc[tt][1], cs, -mnew));
      const float p2 = __builtin_amdgcn_exp2f(fmaf(sacc[tt][2], cs, -mnew));
      const float p3 = __builtin_amdgcn_exp2f(fmaf(sacc[tt][3], cs, -mnew));
      rsum += (p0 + p1) + (p2 + p3);
      union { f16x4 v; h16x2 h[2]; } u;
      u.h[0] = __builtin_amdgcn_cvt_pkrtz(p0, p1);
      u.h[1] = __builtin_amdgcn_cvt_pkrtz(p2, p3);
      const int c = 2 * tt + (hi >> 1);
      *(f16x4*)(Pw + lo * 64 + (((c ^ lo) & 7) << 3) + ((hi & 1) << 2)) = u.v;
    }
    rsum += __shfl_xor(rsum, 16, 64);
    rsum += __shfl_xor(rsum, 32, 64);
    l_run = l_run * alpha + rsum;
    m_run = mnew;
    if (nsk) {
      #pragma unroll
      for (int dt = 0; dt < 4; ++dt) accO[dt] *= alpha;
    }

    // O^T += V^T · P^T (Pw wave-private: no barrier before reads)
    #pragma unroll
    for (int ks2 = 0; ks2 < 2; ++ks2) {
      const int c = 4 * ks2 + hi;
      const f16x8 pf = *(const f16x8*)(Pw + lo * 64 + (((c ^ lo) & 7) << 3));
      #pragma unroll
      for (int dt = 0; dt < 4; ++dt) {
        const int dd = dt * 16 + lo;
        const f16x8 vf = *(const f16x8*)(Vc + dd * 64 + (((c ^ dd) & 7) << 3));
        accO[dt] = MFMA16(vf, pf, accO[dt]);
      }
    }
  };

  // one pipelined step: prefetch next tile, counted wait for current, compute
  auto step = [&](int tnext0, int cb, bool pre) {
    if (pre) {
      issue(tnext0, cb ^ 1);
      asm volatile("s_waitcnt vmcnt(2)" ::: "memory");   // tile cb landed; next stays in flight
    } else {
      asm volatile("s_waitcnt vmcnt(0)" ::: "memory");   // last tile: full drain
    }
    __builtin_amdgcn_sched_barrier(0);
    __builtin_amdgcn_s_barrier();       // cross-wave: all tile-cb segments visible
    compute(cb);
    __builtin_amdgcn_sched_barrier(0);
    __builtin_amdgcn_s_barrier();       // all reads of buf cb done before it is re-DMA'd
  };

  #pragma unroll 1
  for (int it = 0; it < 7; ++it) {      // tiles 0..13
    step((2 * it + 1) << 6, 0, true);
    step((2 * it + 2) << 6, 1, true);
  }
  step(15 << 6, 0, true);               // tile 14, prefetch tile 15
  step(0, 1, false);                    // tile 15, no prefetch

  // O^T C layout: col=lo=q, row=hi*4+i (+16*dt) = d. Write Oh [16384,576] swizzled.
  const float inv = 1.f / l_run;
  const int b = bh / 9, hh = bh - b * 9;
  const int rq = (b << 10) + q0 + wave * 16 + lo;
  #pragma unroll
  for (int dt = 0; dt < 4; ++dt) {
    union { f16x4 v; h16x2 h[2]; } u;
    u.h[0] = __builtin_amdgcn_cvt_pkrtz(accO[dt][0] * inv, accO[dt][1] * inv);
    u.h[1] = __builtin_amdgcn_cvt_pkrtz(accO[dt][2] * inv, accO[dt][3] * inv);
    const int c = hh * 8 + dt * 2 + (hi >> 1);
    const int pos = (c & ~7) | ((c ^ rq) & 7);
    *(f16x4*)(Og + rq * 576 + pos * 8 + ((hi & 1) << 2)) = u.v;
  }
}

// ---------------------------------------------------------------- GEMM3: out = O @ proj_w^T + b (fp32 out)
// 1-D grid 768 = 8 XCD x 16 m-tiles x 6 n-tiles, n-inner: A-panel L2-hot per XCD.
__global__ __launch_bounds__(256, 4) void gemm3_proj(const _Float16* __restrict__ A,
                                                     const _Float16* __restrict__ Bw,
                                                     const float* __restrict__ bias,
                                                     float* __restrict__ out) {
  __shared__ __align__(16) _Float16 As[128 * 64];
  __shared__ __align__(16) _Float16 Bs[128 * 64];
  const int tid = threadIdx.x;
  const int wave = tid >> 6, lane = tid & 63;
  const int lo = lane & 15, hi = lane >> 4;
  const int wm = (wave >> 1) * 64, wn = (wave & 1) * 64;
  const int g = blockIdx.x;
  const int xcd = g & 7, i = g >> 3;            // i in [0,96)
  const int mt = i / 6, ntl = i - mt * 6;       // 16 m-tiles/XCD, 6 n-tiles
  const int m0 = (xcd * 16 + mt) * 128, n0 = ntl * 128;
  f32x4 acc[4][4] = {};
  for (int k0 = 0; k0 < 576; k0 += 64) {
    __syncthreads();
    #pragma unroll
    for (int j = 0; j < 4; ++j) {
      const int seg = wave * 4 + j;
      const int gr = seg * 8 + (lane >> 3), gc = (lane & 7) << 3;
      gld16(A + (m0 + gr) * 576 + k0 + gc, As + seg * 512);
      gld16(Bw + (n0 + gr) * 576 + k0 + gc, Bs + seg * 512);
    }
    __syncthreads();
    #pragma unroll
    for (int ks = 0; ks < 2; ++ks) {
      f16x8 af[4], bf[4];
      const int p = ((ks * 4 + hi) ^ (lo & 7)) << 3;
      #pragma unroll
      for (int t = 0; t < 4; ++t) {
        af[t] = *(const f16x8*)(As + (wm + t * 16 + lo) * 64 + p);
        bf[t] = *(const f16x8*)(Bs + (wn + t * 16 + lo) * 64 + p);
      }
      #pragma unroll
      for (int mt2 = 0; mt2 < 4; ++mt2)
        #pragma unroll
        for (int nt = 0; nt < 4; ++nt)
          acc[mt2][nt] = MFMA16(af[mt2], bf[nt], acc[mt2][nt]);
    }
  }
  #pragma unroll
  for (int nt = 0; nt < 4; ++nt) {
    const int n = n0 + wn + nt * 16 + lo;
    const float bv = bias[n];
    #pragma unroll
    for (int mt2 = 0; mt2 < 4; ++mt2) {
      const int mrow = m0 + wm + mt2 * 16 + hi * 4;
      #pragma unroll
      for (int i2 = 0; i2 < 4; ++i2)
        out[(mrow + i2) * 768 + n] = acc[mt2][nt][i2] + bv;
    }
  }
}

// ---------------------------------------------------------------- launch
extern "C" void kernel_launch(void* const* d_in, const int* in_sizes, int n_in,
                              void* d_out, int out_size, void* d_ws, size_t ws_size,
                              hipStream_t stream) {
  const float* x      = (const float*)d_in[0];
  const float* qkv_w  = (const float*)d_in[1];
  const float* qkv_b  = (const float*)d_in[2];
  const float* proj_w = (const float*)d_in[3];
  const float* proj_b = (const float*)d_in[4];
  float* out = (float*)d_out;

  char* ws = (char*)d_ws;
  _Float16* x16 = (_Float16*)(ws + 0);          // 16384*768*2  swz
  _Float16* w1p = (_Float16*)(ws + 25165824);   // 1792*768*2   swz, rows>=1728 zero
  _Float16* w2h = (_Float16*)(ws + 27918336);   // 768*576*2    swz
  _Float16* Qh  = (_Float16*)(ws + 28803072);   // [bh][1024][64] plain
  _Float16* Kh  = (_Float16*)(ws + 47677440);   // [bh][1024][64] swz
  _Float16* Vth = (_Float16*)(ws + 66551808);   // [bh][64][1024] transposed swz
  _Float16* Oh  = (_Float16*)(ws + 85426176);   // [16384][576] swz

  cvt_swz<<<6144, 256, 0, stream>>>(x, x16, 16384, 96, 16384 * 96);
  cvt_swz<<<672, 256, 0, stream>>>(qkv_w, w1p, 1728, 96, 1792 * 96);
  cvt_swz<<<216, 256, 0, stream>>>(proj_w, w2h, 768, 72, 768 * 72);
  gemm1_qkv<<<1792, 256, 0, stream>>>(x16, w1p, qkv_b, Qh, Kh, Vth);
  attn_fused<<<1152, 512, 0, stream>>>(Qh, Kh, Vth, Oh);
  gemm3_proj<<<768, 256, 0, stream>>>(Oh, w2h, proj_b, out);
}